// Round 2
// baseline (142.709 us; speedup 1.0000x reference)
//
#include <hip/hip_runtime.h>
#include <hip/hip_bf16.h>

typedef __attribute__((ext_vector_type(8))) short bf16x8;
typedef __attribute__((ext_vector_type(4))) float f32x4;

static constexpr int Bb = 64;
static constexpr int Qq = 32;
static constexpr int LD = 4096;
static constexpr int Dd = 128;
static constexpr int SPLITS = 16;          // L-chunks per batch -> 1024 blocks (4/CU)
static constexpr int CHUNK = LD / SPLITS;  // 256 tokens per block
static constexpr int NWAVE = 4;            // 256 threads
static constexpr int TPW = CHUNK / NWAVE;  // 64 tokens per wave
static constexpr int LTILES = TPW / 16;    // 4 MFMA l-tiles per wave

__device__ __forceinline__ short f2bf(float f) {
  __hip_bfloat16 h = __float2bfloat16(f);
  return *reinterpret_cast<short*>(&h);
}

__device__ __forceinline__ bf16x8 cvt8(float4 a, float4 b) {
  bf16x8 v;
  v[0] = f2bf(a.x); v[1] = f2bf(a.y); v[2] = f2bf(a.z); v[3] = f2bf(a.w);
  v[4] = f2bf(b.x); v[5] = f2bf(b.y); v[6] = f2bf(b.z); v[7] = f2bf(b.w);
  return v;
}

// Fused: per (batch, L-chunk) block computes partial max over its chunk for all
// 32 query tokens, writes pmax[b][s][q]; last-arriving block per batch reduces
// (max over s, sum over q) and writes out[b]. Split-K last-block pattern with
// device-scope fences (XCD L2 non-coherence safe).
__global__ __launch_bounds__(256, 4) void maxsim_fused(
    const float* __restrict__ qe, const float* __restrict__ de,
    float* __restrict__ pmax, unsigned* __restrict__ cnt,
    float* __restrict__ out) {
  const int blk  = blockIdx.x;
  const int b    = blk / SPLITS;
  const int s    = blk % SPLITS;
  const int wave = threadIdx.x >> 6;
  const int lane = threadIdx.x & 63;
  const int lcol = lane & 15;   // MFMA column slot (doc token within tile; q row for A)
  const int lgrp = lane >> 4;   // MFMA k-group

  const float* __restrict__ qb = qe + (size_t)b * Qq * Dd;
  const float* __restrict__ db = de + (size_t)b * LD * Dd;

  // A fragments (query tile, M=32 -> 2 M-tiles of 16), in registers all kernel.
  // Same lane->k rule for A and B, so any k-slot permutation cancels.
  bf16x8 afrag[2][4];
#pragma unroll
  for (int mt = 0; mt < 2; ++mt)
#pragma unroll
    for (int kb = 0; kb < 4; ++kb) {
      const float* p = qb + (size_t)(mt * 16 + lcol) * Dd + kb * 32 + lgrp * 8;
      afrag[mt][kb] = cvt8(*reinterpret_cast<const float4*>(p),
                           *reinterpret_cast<const float4*>(p + 4));
    }

  float mx0[4], mx1[4];
#pragma unroll
  for (int i = 0; i < 4; ++i) { mx0[i] = -3.4e38f; mx1[i] = -3.4e38f; }

  const int tok0 = s * CHUNK + wave * TPW;
  // Per-lane base: row = tok0 + lcol, k-slice = lgrp*8. Tile lt adds 16 rows.
  const float* __restrict__ lanebase = db + (size_t)(tok0 + lcol) * Dd + lgrp * 8;

  // Prefetch pipeline: nraw holds the NEXT tile's raw floats; convert current,
  // issue next loads, then MFMA — loads overlap cvt+MFMA of current tile.
  float4 nraw[8];
#pragma unroll
  for (int kb = 0; kb < 4; ++kb) {
    nraw[2 * kb]     = *reinterpret_cast<const float4*>(lanebase + kb * 32);
    nraw[2 * kb + 1] = *reinterpret_cast<const float4*>(lanebase + kb * 32 + 4);
  }

#pragma unroll
  for (int lt = 0; lt < LTILES; ++lt) {
    bf16x8 bfrag[4];
#pragma unroll
    for (int kb = 0; kb < 4; ++kb)
      bfrag[kb] = cvt8(nraw[2 * kb], nraw[2 * kb + 1]);
    if (lt + 1 < LTILES) {
      const float* nb = lanebase + (size_t)(lt + 1) * 16 * Dd;
#pragma unroll
      for (int kb = 0; kb < 4; ++kb) {
        nraw[2 * kb]     = *reinterpret_cast<const float4*>(nb + kb * 32);
        nraw[2 * kb + 1] = *reinterpret_cast<const float4*>(nb + kb * 32 + 4);
      }
    }
    f32x4 acc0 = {0.f, 0.f, 0.f, 0.f};
    f32x4 acc1 = {0.f, 0.f, 0.f, 0.f};
#pragma unroll
    for (int kb = 0; kb < 4; ++kb) {
      acc0 = __builtin_amdgcn_mfma_f32_16x16x32_bf16(afrag[0][kb], bfrag[kb], acc0, 0, 0, 0);
      acc1 = __builtin_amdgcn_mfma_f32_16x16x32_bf16(afrag[1][kb], bfrag[kb], acc1, 0, 0, 0);
    }
    // C/D layout (m89-verified): col = lane&15 (doc token), row = lgrp*4 + i (query).
#pragma unroll
    for (int i = 0; i < 4; ++i) {
      mx0[i] = fmaxf(mx0[i], acc0[i]);
      mx1[i] = fmaxf(mx1[i], acc1[i]);
    }
  }

  // Max over doc-token columns = butterfly over the low 4 lane bits.
#pragma unroll
  for (int off = 1; off < 16; off <<= 1) {
#pragma unroll
    for (int i = 0; i < 4; ++i) {
      mx0[i] = fmaxf(mx0[i], __shfl_xor(mx0[i], off));
      mx1[i] = fmaxf(mx1[i], __shfl_xor(mx1[i], off));
    }
  }

  __shared__ float smax[NWAVE][Qq];
  if (lcol == 0) {
#pragma unroll
    for (int i = 0; i < 4; ++i) {
      smax[wave][lgrp * 4 + i]      = mx0[i];
      smax[wave][16 + lgrp * 4 + i] = mx1[i];
    }
  }
  __syncthreads();
  if (threadIdx.x < Qq) {
    const int qi = threadIdx.x;
    float m = fmaxf(fmaxf(smax[0][qi], smax[1][qi]),
                    fmaxf(smax[2][qi], smax[3][qi]));
    pmax[((size_t)b * SPLITS + s) * Qq + qi] = m;
  }

  // ---- fused cross-block finish (split-K last-block pattern) ----
  __threadfence();            // release: our pmax stores reach device scope
  __shared__ unsigned s_old;
  __syncthreads();            // all pmax stores + fences done before the atomic
  if (threadIdx.x == 0) s_old = atomicAdd(&cnt[b], 1u);
  __syncthreads();
  if (s_old == SPLITS - 1 && wave == 0) {
    __threadfence();          // acquire side
    const int qi = lane & 31;
    const int sh = lane >> 5; // two halves of the split axis
    float m = -3.4e38f;
#pragma unroll
    for (int ss = 0; ss < SPLITS / 2; ++ss) {
      float v = __hip_atomic_load(
          &pmax[((size_t)b * SPLITS + sh * (SPLITS / 2) + ss) * Qq + qi],
          __ATOMIC_RELAXED, __HIP_MEMORY_SCOPE_AGENT);
      m = fmaxf(m, v);
    }
    m = fmaxf(m, __shfl_xor(m, 32));   // combine the two split halves
    float v = m;
#pragma unroll
    for (int off = 1; off < 32; off <<= 1) v += __shfl_xor(v, off);
    if (lane == 0) out[b] = v;
  }
}

extern "C" void kernel_launch(void* const* d_in, const int* in_sizes, int n_in,
                              void* d_out, int out_size, void* d_ws, size_t ws_size,
                              hipStream_t stream) {
  const float* qe = (const float*)d_in[0];  // [64,32,128] f32
  const float* de = (const float*)d_in[1];  // [64,4096,128] f32
  float* out  = (float*)d_out;              // [64] f32
  float* pmax = (float*)d_ws;               // [64][16][32] f32 = 128 KB
  unsigned* cnt = (unsigned*)((char*)d_ws + (size_t)Bb * SPLITS * Qq * sizeof(float));

  hipMemsetAsync(cnt, 0, Bb * sizeof(unsigned), stream);  // capture-safe node
  maxsim_fused<<<Bb * SPLITS, 256, 0, stream>>>(qe, de, pmax, cnt, out);
}

// Round 3
// 38.355 us; speedup vs baseline: 3.7208x; 3.7208x over previous
//
#include <hip/hip_runtime.h>
#include <hip/hip_bf16.h>

typedef __attribute__((ext_vector_type(8))) short bf16x8;
typedef __attribute__((ext_vector_type(4))) float f32x4;

static constexpr int Bb = 64;
static constexpr int Qq = 32;
static constexpr int LD = 4096;
static constexpr int Dd = 128;
static constexpr int SPLITS = 16;          // L-chunks per batch -> 1024 blocks (4/CU)
static constexpr int CHUNK = LD / SPLITS;  // 256 tokens per block
static constexpr int NWAVE = 4;            // 256 threads
static constexpr int TPW = CHUNK / NWAVE;  // 64 tokens per wave
static constexpr int LTILES = TPW / 16;    // 4 MFMA l-tiles per wave

__device__ __forceinline__ short f2bf(float f) {
  __hip_bfloat16 h = __float2bfloat16(f);
  return *reinterpret_cast<short*>(&h);
}

__device__ __forceinline__ bf16x8 cvt8(float4 a, float4 b) {
  bf16x8 v;
  v[0] = f2bf(a.x); v[1] = f2bf(a.y); v[2] = f2bf(a.z); v[3] = f2bf(a.w);
  v[4] = f2bf(b.x); v[5] = f2bf(b.y); v[6] = f2bf(b.z); v[7] = f2bf(b.w);
  return v;
}

// Fused split-L MaxSim. Cross-block handoff uses ONLY device-scope (AGENT)
// relaxed atomics on the 2KB pmax region (sc1 write-through, bypasses the
// non-coherent per-XCD L2s). NO __threadfence — an agent fence on gfx950
// emits buffer_wbl2/buffer_inv which invalidates the whole L2 per block and
// collapsed R2 to 385 GB/s. Ordering: __syncthreads drains vmcnt(0), so the
// sc1 pmax stores are at the L3 coherence point before the arrive-atomic.
__global__ __launch_bounds__(256, 4) void maxsim_fused(
    const float* __restrict__ qe, const float* __restrict__ de,
    float* __restrict__ pmax, unsigned* __restrict__ cnt,
    float* __restrict__ out) {
  const int blk  = blockIdx.x;
  const int b    = blk / SPLITS;
  const int s    = blk % SPLITS;
  const int wave = threadIdx.x >> 6;
  const int lane = threadIdx.x & 63;
  const int lcol = lane & 15;   // MFMA column slot (doc token within tile; q row for A)
  const int lgrp = lane >> 4;   // MFMA k-group

  const float* __restrict__ qb = qe + (size_t)b * Qq * Dd;
  const float* __restrict__ db = de + (size_t)b * LD * Dd;

  // A fragments (query tile, M=32 -> 2 M-tiles of 16), in registers all kernel.
  // Same lane->k rule for A and B, so any k-slot permutation cancels.
  bf16x8 afrag[2][4];
#pragma unroll
  for (int mt = 0; mt < 2; ++mt)
#pragma unroll
    for (int kb = 0; kb < 4; ++kb) {
      const float* p = qb + (size_t)(mt * 16 + lcol) * Dd + kb * 32 + lgrp * 8;
      afrag[mt][kb] = cvt8(*reinterpret_cast<const float4*>(p),
                           *reinterpret_cast<const float4*>(p + 4));
    }

  float mx0[4], mx1[4];
#pragma unroll
  for (int i = 0; i < 4; ++i) { mx0[i] = -3.4e38f; mx1[i] = -3.4e38f; }

  const int tok0 = s * CHUNK + wave * TPW;
  // Per-lane base: row = tok0 + lcol, k-slice = lgrp*8. Tile lt adds 16 rows.
  const float* __restrict__ lanebase = db + (size_t)(tok0 + lcol) * Dd + lgrp * 8;

  // Prefetch pipeline: nraw holds the NEXT tile's raw floats.
  float4 nraw[8];
#pragma unroll
  for (int kb = 0; kb < 4; ++kb) {
    nraw[2 * kb]     = *reinterpret_cast<const float4*>(lanebase + kb * 32);
    nraw[2 * kb + 1] = *reinterpret_cast<const float4*>(lanebase + kb * 32 + 4);
  }

#pragma unroll
  for (int lt = 0; lt < LTILES; ++lt) {
    bf16x8 bfrag[4];
#pragma unroll
    for (int kb = 0; kb < 4; ++kb)
      bfrag[kb] = cvt8(nraw[2 * kb], nraw[2 * kb + 1]);
    if (lt + 1 < LTILES) {
      const float* nb = lanebase + (size_t)(lt + 1) * 16 * Dd;
#pragma unroll
      for (int kb = 0; kb < 4; ++kb) {
        nraw[2 * kb]     = *reinterpret_cast<const float4*>(nb + kb * 32);
        nraw[2 * kb + 1] = *reinterpret_cast<const float4*>(nb + kb * 32 + 4);
      }
    }
    f32x4 acc0 = {0.f, 0.f, 0.f, 0.f};
    f32x4 acc1 = {0.f, 0.f, 0.f, 0.f};
#pragma unroll
    for (int kb = 0; kb < 4; ++kb) {
      acc0 = __builtin_amdgcn_mfma_f32_16x16x32_bf16(afrag[0][kb], bfrag[kb], acc0, 0, 0, 0);
      acc1 = __builtin_amdgcn_mfma_f32_16x16x32_bf16(afrag[1][kb], bfrag[kb], acc1, 0, 0, 0);
    }
    // C/D layout (m89-verified): col = lane&15 (doc token), row = lgrp*4 + i (query).
#pragma unroll
    for (int i = 0; i < 4; ++i) {
      mx0[i] = fmaxf(mx0[i], acc0[i]);
      mx1[i] = fmaxf(mx1[i], acc1[i]);
    }
  }

  // Max over doc-token columns = butterfly over the low 4 lane bits.
#pragma unroll
  for (int off = 1; off < 16; off <<= 1) {
#pragma unroll
    for (int i = 0; i < 4; ++i) {
      mx0[i] = fmaxf(mx0[i], __shfl_xor(mx0[i], off));
      mx1[i] = fmaxf(mx1[i], __shfl_xor(mx1[i], off));
    }
  }

  __shared__ float smax[NWAVE][Qq];
  if (lcol == 0) {
#pragma unroll
    for (int i = 0; i < 4; ++i) {
      smax[wave][lgrp * 4 + i]      = mx0[i];
      smax[wave][16 + lgrp * 4 + i] = mx1[i];
    }
  }
  __syncthreads();
  if (threadIdx.x < Qq) {
    const int qi = threadIdx.x;
    float m = fmaxf(fmaxf(smax[0][qi], smax[1][qi]),
                    fmaxf(smax[2][qi], smax[3][qi]));
    // Coherent (sc1) store — visible at L3 once vmcnt drains; no L2 flush.
    __hip_atomic_store(&pmax[((size_t)b * SPLITS + s) * Qq + qi], m,
                       __ATOMIC_RELAXED, __HIP_MEMORY_SCOPE_AGENT);
  }

  // ---- fused cross-block finish (split-K last-block pattern, fence-free) ----
  __shared__ unsigned s_old;
  __syncthreads();  // drains vmcnt(0): sc1 pmax stores are at coherence point
  if (threadIdx.x == 0)
    s_old = __hip_atomic_fetch_add(&cnt[b], 1u, __ATOMIC_RELAXED,
                                   __HIP_MEMORY_SCOPE_AGENT);
  __syncthreads();
  if (s_old == SPLITS - 1 && wave == 0) {
    const int qi = lane & 31;
    const int sh = lane >> 5; // two halves of the split axis
    float m = -3.4e38f;
#pragma unroll
    for (int ss = 0; ss < SPLITS / 2; ++ss) {
      float v = __hip_atomic_load(
          &pmax[((size_t)b * SPLITS + sh * (SPLITS / 2) + ss) * Qq + qi],
          __ATOMIC_RELAXED, __HIP_MEMORY_SCOPE_AGENT);
      m = fmaxf(m, v);
    }
    m = fmaxf(m, __shfl_xor(m, 32));   // combine the two split halves
    float v = m;
#pragma unroll
    for (int off = 1; off < 32; off <<= 1) v += __shfl_xor(v, off);
    if (lane == 0) out[b] = v;
  }
}

extern "C" void kernel_launch(void* const* d_in, const int* in_sizes, int n_in,
                              void* d_out, int out_size, void* d_ws, size_t ws_size,
                              hipStream_t stream) {
  const float* qe = (const float*)d_in[0];  // [64,32,128] f32
  const float* de = (const float*)d_in[1];  // [64,4096,128] f32
  float* out  = (float*)d_out;              // [64] f32
  float* pmax = (float*)d_ws;               // [64][16][32] f32 = 128 KB
  unsigned* cnt = (unsigned*)((char*)d_ws + (size_t)Bb * SPLITS * Qq * sizeof(float));

  hipMemsetAsync(cnt, 0, Bb * sizeof(unsigned), stream);  // capture-safe node
  maxsim_fused<<<Bb * SPLITS, 256, 0, stream>>>(qe, de, pmax, cnt, out);
}